// Round 8
// baseline (467.828 us; speedup 1.0000x reference)
//
#include <hip/hip_runtime.h>

#define NN 100000
#define NE 3200000
#define NQ (NE / 4)            // 800000 int4 quads

// ---- bucketed-scatter plan constants ----
#define NCHUNK 32
#define CHUNK 3125             // 32 * 3125 = 100000 exactly; 12.5 KB LDS
#define NBB 512                // bucket blocks
#define BCAP 320               // per-(chunk,block) capacity: mean 195 + 9 sigma
#define NSLICE 16              // scatter slices
#define GPS (NBB / NSLICE)     // segments per scatter slice = 32

// --------------------------------------------------------------------------
// Bucket: partition edges by dst-chunk into per-(chunk,block) segments.
// Also zeroes the 64 ready counters used by the last-block reductions.
// Packed entry: dst_local (12b) << 17 | src (17b).
__global__ __launch_bounds__(1024) void bucket_kernel(
        const int4* __restrict__ src4, const int4* __restrict__ dst4,
        unsigned* __restrict__ bkt, int* __restrict__ counts,
        int* __restrict__ ready) {
    __shared__ int cnt[NCHUNK];
    if (threadIdx.x < NCHUNK) cnt[threadIdx.x] = 0;
    if (blockIdx.x == 0 && threadIdx.x < 2 * NCHUNK) ready[threadIdx.x] = 0;
    __syncthreads();
    const int b = blockIdx.x;
    const int q0 = (int)(((long long)b * NQ) / NBB);
    const int q1 = (int)(((long long)(b + 1) * NQ) / NBB);
    for (int q = q0 + threadIdx.x; q < q1; q += 1024) {
        const int4 d = dst4[q];
        const int4 s = src4[q];
        const int dd[4] = {d.x, d.y, d.z, d.w};
        const int ss[4] = {s.x, s.y, s.z, s.w};
#pragma unroll
        for (int j = 0; j < 4; ++j) {
            const int c = dd[j] / CHUNK;                  // magic-mul div
            const int slot = atomicAdd(&cnt[c], 1);
            bkt[((size_t)c * NBB + b) * BCAP + slot] =
                ((unsigned)(dd[j] - c * CHUNK) << 17) | (unsigned)ss[j];
        }
    }
    __syncthreads();
    if (threadIdx.x < NCHUNK)
        counts[threadIdx.x * NBB + b] = cnt[threadIdx.x];
}

// --------------------------------------------------------------------------
// Fused scatter+reduce: block (s,c) drains 32 segments (2 per wave) into the
// 12.5 KB LDS chunk accumulator and writes one dense partial. The LAST block
// to finish chunk c (device-scope ready counter) re-reads the 16 partials
// and applies the per-node epilogue:
//   PASS 0: sbuf[i] = sum_j relu(agg*W1[j]+b1[j]) * W2[j]
//   PASS 1: out[i]  = relu(agg + b2)
template <int PASS>
__global__ __launch_bounds__(1024) void scatter_fused_kernel(
        const float* __restrict__ h,
        const unsigned* __restrict__ bkt, const int* __restrict__ counts,
        float* __restrict__ partial, int* __restrict__ ready,
        const float* __restrict__ W1, const float* __restrict__ b1,
        const float* __restrict__ W2, const float* __restrict__ b2,
        float* __restrict__ res) {
    __shared__ float acc[CHUNK];
    __shared__ int isLast;
    const int s = blockIdx.x, c = blockIdx.y;
    for (int i = threadIdx.x; i < CHUNK; i += 1024) acc[i] = 0.0f;
    __syncthreads();
    const int lane = threadIdx.x & 63;
    const int w = threadIdx.x >> 6;
#pragma unroll
    for (int k = 0; k < 2; ++k) {
        const int b = s * GPS + w + k * 16;
        const int n = counts[c * NBB + b];
        const unsigned* bp = bkt + ((size_t)c * NBB + b) * BCAP;
        const uint4* bp4 = (const uint4*)bp;
        const int n4 = n >> 2;
        for (int q = lane; q < n4; q += 64) {
            const uint4 e = bp4[q];
            atomicAdd(&acc[e.x >> 17], h[e.x & 0x1FFFF]);
            atomicAdd(&acc[e.y >> 17], h[e.y & 0x1FFFF]);
            atomicAdd(&acc[e.z >> 17], h[e.z & 0x1FFFF]);
            atomicAdd(&acc[e.w >> 17], h[e.w & 0x1FFFF]);
        }
        const int base = n4 << 2;
        if (base + lane < n) {
            const unsigned e = bp[base + lane];
            atomicAdd(&acc[e >> 17], h[e & 0x1FFFF]);
        }
    }
    __syncthreads();
    float* outp = partial + ((size_t)c * NSLICE + s) * CHUNK;
    for (int i = threadIdx.x; i < CHUNK; i += 1024) outp[i] = acc[i];

    // ---- last-block reduction for this chunk ----
    __threadfence();                       // release our partial stores
    if (threadIdx.x == 0) {
        const int old = atomicAdd(&ready[PASS * NCHUNK + c], 1);
        isLast = (old == NSLICE - 1);
    }
    __syncthreads();
    if (!isLast) return;
    __threadfence();                       // acquire other blocks' partials
    const float* base = partial + (size_t)c * NSLICE * CHUNK;
    for (int i = threadIdx.x; i < CHUNK; i += 1024) {
        float a = 0.0f;
#pragma unroll
        for (int t = 0; t < NSLICE; ++t) a += base[(size_t)t * CHUNK + i];
        if (PASS == 0) {
            float r = 0.0f;
#pragma unroll
            for (int j = 0; j < 16; ++j)
                r = fmaf(fmaxf(fmaf(a, W1[j], b1[j]), 0.0f), W2[j], r);
            res[c * CHUNK + i] = r;
        } else {
            res[c * CHUNK + i] = fmaxf(a + b2[0], 0.0f);
        }
    }
}

// ---------------- Fallback: global-atomic path ------------------------------
__global__ void zero_kernel(float* __restrict__ p, int n) {
    int i = blockIdx.x * blockDim.x + threadIdx.x;
    int st = gridDim.x * blockDim.x;
    for (; i < n; i += st) p[i] = 0.0f;
}
__global__ __launch_bounds__(256) void edge_scatter_kernel(
        const float* __restrict__ h, const int4* __restrict__ src4,
        const int4* __restrict__ dst4, float* __restrict__ agg, int nquad) {
    int i = blockIdx.x * blockDim.x + threadIdx.x;
    if (i >= nquad) return;
    int4 s = src4[i]; int4 d = dst4[i];
    atomicAdd(&agg[d.x], h[s.x]);
    atomicAdd(&agg[d.y], h[s.y]);
    atomicAdd(&agg[d.z], h[s.z]);
    atomicAdd(&agg[d.w], h[s.w]);
}
__global__ __launch_bounds__(256) void mlp_kernel(
        const float* __restrict__ agg1, const float* __restrict__ W1,
        const float* __restrict__ b1, const float* __restrict__ W2,
        float* __restrict__ sout, int n) {
    int i = blockIdx.x * blockDim.x + threadIdx.x;
    if (i >= n) return;
    float a = agg1[i], r = 0.0f;
#pragma unroll
    for (int j = 0; j < 16; ++j)
        r = fmaf(fmaxf(fmaf(a, W1[j], b1[j]), 0.0f), W2[j], r);
    sout[i] = r;
}
__global__ __launch_bounds__(256) void finalize_kernel(
        float* __restrict__ out, const float* __restrict__ b2, int n) {
    int i = blockIdx.x * blockDim.x + threadIdx.x;
    if (i >= n) return;
    out[i] = fmaxf(out[i] + b2[0], 0.0f);
}

extern "C" void kernel_launch(void* const* d_in, const int* in_sizes, int n_in,
                              void* d_out, int out_size, void* d_ws, size_t ws_size,
                              hipStream_t stream) {
    const float* features = (const float*)d_in[0];
    const int*   src      = (const int*)d_in[1];
    const int*   dst      = (const int*)d_in[2];
    const float* W1       = (const float*)d_in[3];
    const float* b1       = (const float*)d_in[4];
    const float* W2       = (const float*)d_in[5];
    const float* b2       = (const float*)d_in[6];
    float* out = (float*)d_out;

    const int4* src4 = (const int4*)src;
    const int4* dst4 = (const int4*)dst;

    // Plan A: bucketed scatter, 3 dispatches (~28 MB ws)
    {
        const size_t bkt_elems  = (size_t)NCHUNK * NBB * BCAP;       // 5.24M u32
        const size_t cnt_elems  = (size_t)NCHUNK * NBB;              // 16384 int
        const size_t part_elems = (size_t)NCHUNK * NSLICE * CHUNK;   // 1.6M f32
        const size_t need = (bkt_elems + cnt_elems + part_elems + NN + 64) * 4;
        if (ws_size >= need) {
            unsigned* bkt  = (unsigned*)d_ws;
            int* counts    = (int*)(bkt + bkt_elems);
            float* partial = (float*)(counts + cnt_elems);
            float* sbuf    = partial + part_elems;
            int* ready     = (int*)(sbuf + NN);

            bucket_kernel<<<NBB, 1024, 0, stream>>>(src4, dst4, bkt, counts, ready);
            dim3 g(NSLICE, NCHUNK);
            scatter_fused_kernel<0><<<g, 1024, 0, stream>>>(
                features, bkt, counts, partial, ready, W1, b1, W2, b2, sbuf);
            scatter_fused_kernel<1><<<g, 1024, 0, stream>>>(
                sbuf, bkt, counts, partial, ready, W1, b1, W2, b2, out);
            return;
        }
    }
    // Fallback: global atomics
    {
        float* agg1 = (float*)d_ws;
        float* sbuf = agg1 + NN;
        const int eb = (NQ + 255) / 256;
        const int nb = (NN + 255) / 256;
        zero_kernel<<<256, 256, 0, stream>>>(agg1, NN);
        edge_scatter_kernel<<<eb, 256, 0, stream>>>(features, src4, dst4, agg1, NQ);
        mlp_kernel<<<nb, 256, 0, stream>>>(agg1, W1, b1, W2, sbuf, NN);
        zero_kernel<<<256, 256, 0, stream>>>(out, NN);
        edge_scatter_kernel<<<eb, 256, 0, stream>>>(sbuf, src4, dst4, out, NQ);
        finalize_kernel<<<nb, 256, 0, stream>>>(out, b2, NN);
    }
}

// Round 9
// 79.511 us; speedup vs baseline: 5.8838x; 5.8838x over previous
//
#include <hip/hip_runtime.h>

#define NN 100000
#define NE 3200000
#define NQ (NE / 4)            // 800000 int4 quads

// ---- bucketed-scatter plan constants ----
#define NCHUNK 32
#define CHUNK 3125             // 32 * 3125 = 100000 exactly; 12.5 KB LDS
#define NBB 512                // bucket blocks
#define BCAP 320               // per-(chunk,block) capacity: mean 195 + 9 sigma
#define NSLICE 16              // scatter slices
#define GPS (NBB / NSLICE)     // segments per scatter slice = 32

// --------------------------------------------------------------------------
// Bucket: partition edges by dst-chunk; ALSO pre-gather pass-1 values
// (features[src]) into val1[] so scatter-1 is gather-free.
// meta entry: dst_local (12b) << 17 | src (17b); val1: f32, same slot.
__global__ __launch_bounds__(1024) void bucket_kernel(
        const float* __restrict__ features,
        const int4* __restrict__ src4, const int4* __restrict__ dst4,
        unsigned* __restrict__ meta, float* __restrict__ val1,
        int* __restrict__ counts) {
    __shared__ int cnt[NCHUNK];
    if (threadIdx.x < NCHUNK) cnt[threadIdx.x] = 0;
    __syncthreads();
    const int b = blockIdx.x;
    const int q0 = (int)(((long long)b * NQ) / NBB);
    const int q1 = (int)(((long long)(b + 1) * NQ) / NBB);
    for (int q = q0 + threadIdx.x; q < q1; q += 1024) {
        const int4 d = dst4[q];
        const int4 s = src4[q];
        // issue 4 independent gathers first (hide L2 latency under LDS atomics)
        float v0 = features[s.x];
        float v1 = features[s.y];
        float v2 = features[s.z];
        float v3 = features[s.w];
        const int dd[4] = {d.x, d.y, d.z, d.w};
        const int ss[4] = {s.x, s.y, s.z, s.w};
        const float vv[4] = {v0, v1, v2, v3};
#pragma unroll
        for (int j = 0; j < 4; ++j) {
            const int c = dd[j] / CHUNK;                  // magic-mul div
            const int slot = atomicAdd(&cnt[c], 1);
            const size_t pos = ((size_t)c * NBB + b) * BCAP + slot;
            meta[pos] = ((unsigned)(dd[j] - c * CHUNK) << 17) | (unsigned)ss[j];
            val1[pos] = vv[j];
        }
    }
    __syncthreads();
    if (threadIdx.x < NCHUNK)
        counts[threadIdx.x * NBB + b] = cnt[threadIdx.x];
}

// --------------------------------------------------------------------------
// Scatter pass 1: gather-free. Streams (meta, val1) pairs, LDS-accumulates,
// writes one dense partial per (slice, chunk).
__global__ __launch_bounds__(1024) void scatter_val_kernel(
        const unsigned* __restrict__ meta, const float* __restrict__ val1,
        const int* __restrict__ counts, float* __restrict__ partial) {
    __shared__ float acc[CHUNK];
    const int s = blockIdx.x, c = blockIdx.y;
    for (int i = threadIdx.x; i < CHUNK; i += 1024) acc[i] = 0.0f;
    __syncthreads();
    const int lane = threadIdx.x & 63;
    const int w = threadIdx.x >> 6;
#pragma unroll
    for (int k = 0; k < 2; ++k) {
        const int b = s * GPS + w + k * 16;
        const int n = counts[c * NBB + b];
        const size_t seg = ((size_t)c * NBB + b) * BCAP;
        const uint4* m4 = (const uint4*)(meta + seg);
        const float4* v4 = (const float4*)(val1 + seg);
        const int n4 = n >> 2;
        for (int q = lane; q < n4; q += 64) {
            const uint4 m = m4[q];
            const float4 v = v4[q];
            atomicAdd(&acc[m.x >> 17], v.x);
            atomicAdd(&acc[m.y >> 17], v.y);
            atomicAdd(&acc[m.z >> 17], v.z);
            atomicAdd(&acc[m.w >> 17], v.w);
        }
        const int base = n4 << 2;
        if (base + lane < n) {
            atomicAdd(&acc[meta[seg + base + lane] >> 17],
                      val1[seg + base + lane]);
        }
    }
    __syncthreads();
    float* outp = partial + ((size_t)c * NSLICE + s) * CHUNK;
    for (int i = threadIdx.x; i < CHUNK; i += 1024) outp[i] = acc[i];
}

// --------------------------------------------------------------------------
// Scatter pass 2: gathers h (=sbuf) via src packed in meta (R6-proven form).
__global__ __launch_bounds__(1024) void scatter_bkt_kernel(
        const float* __restrict__ h,
        const unsigned* __restrict__ meta, const int* __restrict__ counts,
        float* __restrict__ partial) {
    __shared__ float acc[CHUNK];
    const int s = blockIdx.x, c = blockIdx.y;
    for (int i = threadIdx.x; i < CHUNK; i += 1024) acc[i] = 0.0f;
    __syncthreads();
    const int lane = threadIdx.x & 63;
    const int w = threadIdx.x >> 6;
#pragma unroll
    for (int k = 0; k < 2; ++k) {
        const int b = s * GPS + w + k * 16;
        const int n = counts[c * NBB + b];
        const unsigned* bp = meta + ((size_t)c * NBB + b) * BCAP;
        const uint4* bp4 = (const uint4*)bp;
        const int n4 = n >> 2;
        for (int q = lane; q < n4; q += 64) {
            const uint4 e = bp4[q];
            atomicAdd(&acc[e.x >> 17], h[e.x & 0x1FFFF]);
            atomicAdd(&acc[e.y >> 17], h[e.y & 0x1FFFF]);
            atomicAdd(&acc[e.z >> 17], h[e.z & 0x1FFFF]);
            atomicAdd(&acc[e.w >> 17], h[e.w & 0x1FFFF]);
        }
        const int base = n4 << 2;
        if (base + lane < n) {
            const unsigned e = bp[base + lane];
            atomicAdd(&acc[e >> 17], h[e & 0x1FFFF]);
        }
    }
    __syncthreads();
    float* outp = partial + ((size_t)c * NSLICE + s) * CHUNK;
    for (int i = threadIdx.x; i < CHUNK; i += 1024) outp[i] = acc[i];
}

// agg1 = sum over 16 slice partials; s = sum_j relu(agg1*W1+b1)*W2
__global__ __launch_bounds__(256) void reduce_mlp_kernel(
        const float* __restrict__ partial,
        const float* __restrict__ W1, const float* __restrict__ b1,
        const float* __restrict__ W2,
        float* __restrict__ sout, int n) {
    int i = blockIdx.x * blockDim.x + threadIdx.x;
    if (i >= n) return;
    const int c = i / CHUNK;
    const int idx = i - c * CHUNK;
    const float* base = partial + (size_t)c * NSLICE * CHUNK + idx;
    float a = 0.0f;
#pragma unroll
    for (int s = 0; s < NSLICE; ++s) a += base[(size_t)s * CHUNK];
    float r = 0.0f;
#pragma unroll
    for (int j = 0; j < 16; ++j)
        r = fmaf(fmaxf(fmaf(a, W1[j], b1[j]), 0.0f), W2[j], r);
    sout[i] = r;
}

__global__ __launch_bounds__(256) void reduce_final_kernel(
        const float* __restrict__ partial,
        const float* __restrict__ b2,
        float* __restrict__ out, int n) {
    int i = blockIdx.x * blockDim.x + threadIdx.x;
    if (i >= n) return;
    const int c = i / CHUNK;
    const int idx = i - c * CHUNK;
    const float* base = partial + (size_t)c * NSLICE * CHUNK + idx;
    float a = 0.0f;
#pragma unroll
    for (int s = 0; s < NSLICE; ++s) a += base[(size_t)s * CHUNK];
    out[i] = fmaxf(a + b2[0], 0.0f);
}

// ---------------- Fallback: global-atomic path ------------------------------
__global__ void zero_kernel(float* __restrict__ p, int n) {
    int i = blockIdx.x * blockDim.x + threadIdx.x;
    int st = gridDim.x * blockDim.x;
    for (; i < n; i += st) p[i] = 0.0f;
}
__global__ __launch_bounds__(256) void edge_scatter_kernel(
        const float* __restrict__ h, const int4* __restrict__ src4,
        const int4* __restrict__ dst4, float* __restrict__ agg, int nquad) {
    int i = blockIdx.x * blockDim.x + threadIdx.x;
    if (i >= nquad) return;
    int4 s = src4[i]; int4 d = dst4[i];
    atomicAdd(&agg[d.x], h[s.x]);
    atomicAdd(&agg[d.y], h[s.y]);
    atomicAdd(&agg[d.z], h[s.z]);
    atomicAdd(&agg[d.w], h[s.w]);
}
__global__ __launch_bounds__(256) void mlp_kernel(
        const float* __restrict__ agg1, const float* __restrict__ W1,
        const float* __restrict__ b1, const float* __restrict__ W2,
        float* __restrict__ sout, int n) {
    int i = blockIdx.x * blockDim.x + threadIdx.x;
    if (i >= n) return;
    float a = agg1[i], r = 0.0f;
#pragma unroll
    for (int j = 0; j < 16; ++j)
        r = fmaf(fmaxf(fmaf(a, W1[j], b1[j]), 0.0f), W2[j], r);
    sout[i] = r;
}
__global__ __launch_bounds__(256) void finalize_kernel(
        float* __restrict__ out, const float* __restrict__ b2, int n) {
    int i = blockIdx.x * blockDim.x + threadIdx.x;
    if (i >= n) return;
    out[i] = fmaxf(out[i] + b2[0], 0.0f);
}

extern "C" void kernel_launch(void* const* d_in, const int* in_sizes, int n_in,
                              void* d_out, int out_size, void* d_ws, size_t ws_size,
                              hipStream_t stream) {
    const float* features = (const float*)d_in[0];
    const int*   src      = (const int*)d_in[1];
    const int*   dst      = (const int*)d_in[2];
    const float* W1       = (const float*)d_in[3];
    const float* b1       = (const float*)d_in[4];
    const float* W2       = (const float*)d_in[5];
    const float* b2       = (const float*)d_in[6];
    float* out = (float*)d_out;

    const int4* src4 = (const int4*)src;
    const int4* dst4 = (const int4*)dst;
    const int nb = (NN + 255) / 256;

    // Plan A: bucketed scatter with pass-1 value pre-gather (~49 MB ws)
    {
        const size_t seg_elems  = (size_t)NCHUNK * NBB * BCAP;       // 5.24M
        const size_t cnt_elems  = (size_t)NCHUNK * NBB;              // 16384
        const size_t part_elems = (size_t)NCHUNK * NSLICE * CHUNK;   // 1.6M
        const size_t need = (2 * seg_elems + cnt_elems + part_elems + NN) * 4;
        if (ws_size >= need) {
            unsigned* meta = (unsigned*)d_ws;
            float* val1    = (float*)(meta + seg_elems);
            int* counts    = (int*)(val1 + seg_elems);
            float* partial = (float*)(counts + cnt_elems);
            float* sbuf    = partial + part_elems;

            bucket_kernel<<<NBB, 1024, 0, stream>>>(
                features, src4, dst4, meta, val1, counts);
            dim3 g(NSLICE, NCHUNK);
            scatter_val_kernel<<<g, 1024, 0, stream>>>(meta, val1, counts, partial);
            reduce_mlp_kernel<<<nb, 256, 0, stream>>>(partial, W1, b1, W2, sbuf, NN);
            scatter_bkt_kernel<<<g, 1024, 0, stream>>>(sbuf, meta, counts, partial);
            reduce_final_kernel<<<nb, 256, 0, stream>>>(partial, b2, out, NN);
            return;
        }
    }
    // Fallback: global atomics
    {
        float* agg1 = (float*)d_ws;
        float* sbuf = agg1 + NN;
        const int eb = (NQ + 255) / 256;
        zero_kernel<<<256, 256, 0, stream>>>(agg1, NN);
        edge_scatter_kernel<<<eb, 256, 0, stream>>>(features, src4, dst4, agg1, NQ);
        mlp_kernel<<<nb, 256, 0, stream>>>(agg1, W1, b1, W2, sbuf, NN);
        zero_kernel<<<256, 256, 0, stream>>>(out, NN);
        edge_scatter_kernel<<<eb, 256, 0, stream>>>(sbuf, src4, dst4, out, NQ);
        finalize_kernel<<<nb, 256, 0, stream>>>(out, b2, NN);
    }
}

// Round 10
// 77.724 us; speedup vs baseline: 6.0191x; 1.0230x over previous
//
#include <hip/hip_runtime.h>

#define NN 100000
#define NE 3200000
#define NQ (NE / 4)            // 800000 int4 quads

// ---- counting-sort + banded-scatter constants ----
#define NCHUNK 32
#define CHUNK 3125             // dst chunk: 32*3125 = 100000; 12.5 KB LDS acc
#define NBAND 16
#define BAND 6250              // src band: 25 KB of h -> fits 32 KB L1
#define NKEY (NCHUNK * NBAND)  // 512
#define NBB 256                // counting/placing blocks
#define EPB (NQ / NBB)         // 3125 quads per block (exact)
#define KCAP 6912              // per-key dense capacity: mean 6250 + 8 sigma
#define NSLICE 8               // scatter slices per chunk

// --------------------------------------------------------------------------
// Pass 1: per-(key, block) histogram. key = dst_chunk*16 + src_band.
__global__ __launch_bounds__(1024) void count_kernel(
        const int4* __restrict__ src4, const int4* __restrict__ dst4,
        int* __restrict__ counts) {
    __shared__ int cnt[NKEY];
    if (threadIdx.x < NKEY) cnt[threadIdx.x] = 0;
    __syncthreads();
    const int b = blockIdx.x;
    const int q0 = b * EPB;
    for (int q = q0 + threadIdx.x; q < q0 + EPB; q += 1024) {
        const int4 d = dst4[q];
        const int4 s = src4[q];
        const int dd[4] = {d.x, d.y, d.z, d.w};
        const int ss[4] = {s.x, s.y, s.z, s.w};
#pragma unroll
        for (int j = 0; j < 4; ++j) {
            const int key = (dd[j] / CHUNK) * NBAND + (ss[j] / BAND);
            atomicAdd(&cnt[key], 1);
        }
    }
    __syncthreads();
    if (threadIdx.x < NKEY)
        counts[threadIdx.x * NBB + b] = cnt[threadIdx.x];
}

// --------------------------------------------------------------------------
// Pass 2: per-key exclusive scan over the 256 block counts (1 wave per key).
// offs[key][b] = key*KCAP + prefix; ktot[key] = total.
__global__ __launch_bounds__(64) void scan_kernel(
        const int* __restrict__ counts, int* __restrict__ offs,
        int* __restrict__ ktot) {
    const int k = blockIdx.x;
    const int lane = threadIdx.x;
    int v[4];
    int sum = 0;
#pragma unroll
    for (int i = 0; i < 4; ++i) {
        v[i] = counts[k * NBB + lane * 4 + i];
        sum += v[i];
    }
    int incl = sum;
#pragma unroll
    for (int d = 1; d < 64; d <<= 1) {
        int t = __shfl_up(incl, d);
        if (lane >= d) incl += t;
    }
    int run = incl - sum;              // exclusive base for this lane's 4
    const int base = k * KCAP;
#pragma unroll
    for (int i = 0; i < 4; ++i) {
        offs[k * NBB + lane * 4 + i] = base + run;
        run += v[i];
    }
    if (lane == 63) ktot[k] = incl;
}

// --------------------------------------------------------------------------
// Pass 3: place edges into dense per-key segments.
// meta entry: dst_local(12b) << 17 | src(17b).
__global__ __launch_bounds__(1024) void place_kernel(
        const int4* __restrict__ src4, const int4* __restrict__ dst4,
        const int* __restrict__ offs, unsigned* __restrict__ meta) {
    __shared__ int offs_l[NKEY];
    __shared__ int cnt[NKEY];
    const int b = blockIdx.x;
    if (threadIdx.x < NKEY) {
        offs_l[threadIdx.x] = offs[threadIdx.x * NBB + b];
        cnt[threadIdx.x] = 0;
    }
    __syncthreads();
    const int q0 = b * EPB;
    for (int q = q0 + threadIdx.x; q < q0 + EPB; q += 1024) {
        const int4 d = dst4[q];
        const int4 s = src4[q];
        const int dd[4] = {d.x, d.y, d.z, d.w};
        const int ss[4] = {s.x, s.y, s.z, s.w};
#pragma unroll
        for (int j = 0; j < 4; ++j) {
            const int c = dd[j] / CHUNK;
            const int key = c * NBAND + ss[j] / BAND;
            const int slot = atomicAdd(&cnt[key], 1);
            meta[offs_l[key] + slot] =
                ((unsigned)(dd[j] - c * CHUNK) << 17) | (unsigned)ss[j];
        }
    }
}

// --------------------------------------------------------------------------
// Banded scatter: block (s,c) walks the 16 src-bands of chunk c in order;
// each band's gathers hit a 25 KB L1-resident window of h. Dense coalesced
// meta reads, ~780 active threads per band strip, LDS accumulate, one dense
// partial per (c,s).
__global__ __launch_bounds__(1024) void scatter_band_kernel(
        const float* __restrict__ h,
        const unsigned* __restrict__ meta, const int* __restrict__ ktot,
        float* __restrict__ partial) {
    __shared__ float acc[CHUNK];
    const int s = blockIdx.x, c = blockIdx.y;
    for (int i = threadIdx.x; i < CHUNK; i += 1024) acc[i] = 0.0f;
    __syncthreads();
#pragma unroll
    for (int band = 0; band < NBAND; ++band) {
        const int key = c * NBAND + band;
        const int kt = ktot[key];
        const int lo = (kt * s) >> 3;
        const int hi = (kt * (s + 1)) >> 3;
        const int n = hi - lo;
        if (threadIdx.x < n) {
            const unsigned e = meta[key * KCAP + lo + threadIdx.x];
            atomicAdd(&acc[e >> 17], h[e & 0x1FFFF]);
        }
    }
    __syncthreads();
    float* outp = partial + ((size_t)c * NSLICE + s) * CHUNK;
    for (int i = threadIdx.x; i < CHUNK; i += 1024) outp[i] = acc[i];
}

// agg = sum over 8 slice partials; epilogues as before.
__global__ __launch_bounds__(256) void reduce_mlp_kernel(
        const float* __restrict__ partial,
        const float* __restrict__ W1, const float* __restrict__ b1,
        const float* __restrict__ W2,
        float* __restrict__ sout, int n) {
    int i = blockIdx.x * blockDim.x + threadIdx.x;
    if (i >= n) return;
    const int c = i / CHUNK;
    const int idx = i - c * CHUNK;
    const float* base = partial + (size_t)c * NSLICE * CHUNK + idx;
    float a = 0.0f;
#pragma unroll
    for (int s = 0; s < NSLICE; ++s) a += base[(size_t)s * CHUNK];
    float r = 0.0f;
#pragma unroll
    for (int j = 0; j < 16; ++j)
        r = fmaf(fmaxf(fmaf(a, W1[j], b1[j]), 0.0f), W2[j], r);
    sout[i] = r;
}

__global__ __launch_bounds__(256) void reduce_final_kernel(
        const float* __restrict__ partial,
        const float* __restrict__ b2,
        float* __restrict__ out, int n) {
    int i = blockIdx.x * blockDim.x + threadIdx.x;
    if (i >= n) return;
    const int c = i / CHUNK;
    const int idx = i - c * CHUNK;
    const float* base = partial + (size_t)c * NSLICE * CHUNK + idx;
    float a = 0.0f;
#pragma unroll
    for (int s = 0; s < NSLICE; ++s) a += base[(size_t)s * CHUNK];
    out[i] = fmaxf(a + b2[0], 0.0f);
}

// ---------------- Fallback: global-atomic path ------------------------------
__global__ void zero_kernel(float* __restrict__ p, int n) {
    int i = blockIdx.x * blockDim.x + threadIdx.x;
    int st = gridDim.x * blockDim.x;
    for (; i < n; i += st) p[i] = 0.0f;
}
__global__ __launch_bounds__(256) void edge_scatter_kernel(
        const float* __restrict__ h, const int4* __restrict__ src4,
        const int4* __restrict__ dst4, float* __restrict__ agg, int nquad) {
    int i = blockIdx.x * blockDim.x + threadIdx.x;
    if (i >= nquad) return;
    int4 s = src4[i]; int4 d = dst4[i];
    atomicAdd(&agg[d.x], h[s.x]);
    atomicAdd(&agg[d.y], h[s.y]);
    atomicAdd(&agg[d.z], h[s.z]);
    atomicAdd(&agg[d.w], h[s.w]);
}
__global__ __launch_bounds__(256) void mlp_kernel(
        const float* __restrict__ agg1, const float* __restrict__ W1,
        const float* __restrict__ b1, const float* __restrict__ W2,
        float* __restrict__ sout, int n) {
    int i = blockIdx.x * blockDim.x + threadIdx.x;
    if (i >= n) return;
    float a = agg1[i], r = 0.0f;
#pragma unroll
    for (int j = 0; j < 16; ++j)
        r = fmaf(fmaxf(fmaf(a, W1[j], b1[j]), 0.0f), W2[j], r);
    sout[i] = r;
}
__global__ __launch_bounds__(256) void finalize_kernel(
        float* __restrict__ out, const float* __restrict__ b2, int n) {
    int i = blockIdx.x * blockDim.x + threadIdx.x;
    if (i >= n) return;
    out[i] = fmaxf(out[i] + b2[0], 0.0f);
}

extern "C" void kernel_launch(void* const* d_in, const int* in_sizes, int n_in,
                              void* d_out, int out_size, void* d_ws, size_t ws_size,
                              hipStream_t stream) {
    const float* features = (const float*)d_in[0];
    const int*   src      = (const int*)d_in[1];
    const int*   dst      = (const int*)d_in[2];
    const float* W1       = (const float*)d_in[3];
    const float* b1       = (const float*)d_in[4];
    const float* W2       = (const float*)d_in[5];
    const float* b2       = (const float*)d_in[6];
    float* out = (float*)d_out;

    const int4* src4 = (const int4*)src;
    const int4* dst4 = (const int4*)dst;
    const int nb = (NN + 255) / 256;

    // Plan A: counting-sort + banded scatter (~19 MB ws)
    {
        const size_t cnt_elems  = (size_t)NKEY * NBB;                // 131072
        const size_t ktot_elems = NKEY;
        const size_t meta_elems = (size_t)NKEY * KCAP;               // 3.54M
        const size_t part_elems = (size_t)NCHUNK * NSLICE * CHUNK;   // 800K
        const size_t need =
            (2 * cnt_elems + ktot_elems + meta_elems + part_elems + NN) * 4;
        if (ws_size >= need) {
            int* counts    = (int*)d_ws;
            int* offs      = counts + cnt_elems;
            int* ktot      = offs + cnt_elems;
            unsigned* meta = (unsigned*)(ktot + ktot_elems);
            float* partial = (float*)(meta + meta_elems);
            float* sbuf    = partial + part_elems;

            count_kernel<<<NBB, 1024, 0, stream>>>(src4, dst4, counts);
            scan_kernel<<<NKEY, 64, 0, stream>>>(counts, offs, ktot);
            place_kernel<<<NBB, 1024, 0, stream>>>(src4, dst4, offs, meta);
            dim3 g(NSLICE, NCHUNK);
            scatter_band_kernel<<<g, 1024, 0, stream>>>(features, meta, ktot, partial);
            reduce_mlp_kernel<<<nb, 256, 0, stream>>>(partial, W1, b1, W2, sbuf, NN);
            scatter_band_kernel<<<g, 1024, 0, stream>>>(sbuf, meta, ktot, partial);
            reduce_final_kernel<<<nb, 256, 0, stream>>>(partial, b2, out, NN);
            return;
        }
    }
    // Fallback: global atomics
    {
        float* agg1 = (float*)d_ws;
        float* sbuf = agg1 + NN;
        const int eb = (NQ + 255) / 256;
        zero_kernel<<<256, 256, 0, stream>>>(agg1, NN);
        edge_scatter_kernel<<<eb, 256, 0, stream>>>(features, src4, dst4, agg1, NQ);
        mlp_kernel<<<nb, 256, 0, stream>>>(agg1, W1, b1, W2, sbuf, NN);
        zero_kernel<<<256, 256, 0, stream>>>(out, NN);
        edge_scatter_kernel<<<eb, 256, 0, stream>>>(sbuf, src4, dst4, out, NQ);
        finalize_kernel<<<nb, 256, 0, stream>>>(out, b2, NN);
    }
}